// Round 3
// baseline (788.563 us; speedup 1.0000x reference)
//
#include <hip/hip_runtime.h>
#include <cfloat>
#include <math.h>

// Problem constants
constexpr int H_  = 6;
constexpr int C_  = 64;
constexpr int OV_ = 4;
constexpr int G_  = 3;
constexpr int NVQ_ = 6;
constexpr int K_  = 1024;
constexpr int D_  = 8;
constexpr int B_  = 32;
constexpr int W_  = 2400;
constexpr int T_  = 600;          // W/OV
constexpr int NPOS_ = B_ * T_;    // 19200
constexpr int FIX_ = H_ * C_;     // 384
constexpr int GD_ = 512;

// Output layout (floats, concatenated in return order)
constexpr size_t OUT_ZQ   = 0;
constexpr size_t OUT_IDX  = (size_t)B_ * H_ * W_ * C_;             // 29491200
constexpr size_t OUT_LOSS = OUT_IDX + (size_t)B_ * NVQ_ * G_ * T_; // 29836800

// Workspace layout (bytes)
constexpr size_t WS_EN64 = 0;                                        // double[18432*8]
constexpr size_t WS_EN32 = WS_EN64 + (size_t)G_*NVQ_*K_*D_*8;        // float[18432*8], float2 layout [gi][d2][k]
constexpr size_t WS_ZD   = WS_EN32 + (size_t)G_*NVQ_*K_*D_*4;        // double[3*19200*8]
constexpr size_t WS_LOSS = WS_ZD + (size_t)G_*NPOS_*D_*8;            // double[1]
constexpr size_t WS_ZQ   = WS_LOSS + 64;                             // float[3*19200*8]

// ---------------------------------------------------------------------------
// K1: normalize codebooks in fp64. Outputs:
//   en64[gi][k][d]  - contiguous fp64 rows (exact normalized codewords)
//   en32[gi][d2][k] - fp32 float2-pair transposed layout for LDS screening
// Also zeroes the loss accumulator.
__global__ __launch_bounds__(256) void k1_norm_cb(const float* __restrict__ cb,
                                                  double* __restrict__ en64,
                                                  float* __restrict__ en32,
                                                  double* __restrict__ loss) {
    int tid = blockIdx.x * 256 + threadIdx.x;
    if (tid == 0) loss[0] = 0.0;
    if (tid >= G_ * NVQ_ * K_) return;
    int k  = tid & (K_ - 1);
    int gi = tid >> 10;               // 0..17  (g*6+i)
    const float* row = cb + (size_t)tid * D_;
    double v[D_];
    double ss = 0.0;
#pragma unroll
    for (int d = 0; d < D_; d++) { v[d] = (double)row[d]; ss += v[d] * v[d]; }
    double n = sqrt(ss);
    if (n < 1e-12) n = 1e-12;
    double q[D_];
#pragma unroll
    for (int d = 0; d < D_; d++) q[d] = v[d] / n;   // division to mimic ref
    double* o64 = en64 + (size_t)tid * D_;
#pragma unroll
    for (int d = 0; d < D_; d++) o64[d] = q[d];
    float2* o32 = (float2*)en32;
#pragma unroll
    for (int d2 = 0; d2 < 4; d2++) {
        float2 f;
        f.x = (float)q[2 * d2];
        f.y = (float)q[2 * d2 + 1];
        o32[((size_t)gi * 4 + d2) * K_ + k] = f;
    }
}

// ---------------------------------------------------------------------------
// K2: fold (pre_process) + proj_down with fp64 accumulation.
// Block: 256 threads, 8 positions. LDS zfold layout: p*PSTR + ov*OVS + (c*6+h).
constexpr int PSTR_ = 1548;   // %32 = 12 -> 8 p's hit distinct banks; mult of 4
constexpr int OVS_  = 388;    // > 383; mult of 4

__global__ __launch_bounds__(256) void k2_fold_pd(const float* __restrict__ ze,
                                                  const float* __restrict__ pd,
                                                  double* __restrict__ zd) {
    __shared__ __align__(16) float zf[8 * PSTR_];    // ~49.5 KB
    int tid  = threadIdx.x;
    int pos0 = blockIdx.x * 8;
    // Load: 48 segments (p,h) x 256 contiguous floats; float4 per thread.
#pragma unroll
    for (int it = 0; it < 12; it++) {
        int slot = it * 256 + tid;      // 0..3071
        int seg  = slot >> 6;           // 0..47
        int li   = slot & 63;
        int p = seg / 6, h = seg - p * 6;
        int pos = pos0 + p;
        int b = pos / T_, t = pos - b * T_;
        const float4 vv = *(const float4*)(ze + ((size_t)((b * H_ + h) * W_ + 4 * t)) * C_ + li * 4);
        int ov = li >> 4;
        int c0 = (li & 15) * 4;
        int base = p * PSTR_ + ov * OVS_ + h;
        zf[base + (c0 + 0) * 6] = vv.x;
        zf[base + (c0 + 1) * 6] = vv.y;
        zf[base + (c0 + 2) * 6] = vv.z;
        zf[base + (c0 + 3) * 6] = vv.w;
    }
    __syncthreads();
    if (tid < 192) {
        int p = tid / 24;
        int combo = tid - p * 24;
        int g = combo >> 3, d = combo & 7;
        const float* pdp = pd + ((size_t)g * D_ + d) * GD_;
        int lbase = p * PSTR_;
        double acc = 0.0;
        for (int jj = 0; jj < GD_; jj += 4) {
            int gd  = g * GD_ + jj;
            int ov  = gd / FIX_;
            int rem = gd - ov * FIX_;          // always mult of 4; no ov straddle
            float4 zv = *(const float4*)&zf[lbase + ov * OVS_ + rem];
            float4 pv = *(const float4*)&pdp[jj];
            acc = fma((double)pv.x, (double)zv.x, acc);
            acc = fma((double)pv.y, (double)zv.y, acc);
            acc = fma((double)pv.z, (double)zv.z, acc);
            acc = fma((double)pv.w, (double)zv.w, acc);
        }
        zd[((size_t)g * NPOS_ + pos0 + p) * D_ + d] = acc;
    }
}

// ---------------------------------------------------------------------------
// K3: residual VQ, 6 streams. fp64 residual chain (exact, matches reference);
// sims screened in fp32 from a 32 KB LDS codebook with (max1,idx1,max2)
// tracking; provable-acceptance margin; rare exact fp64 rescore fallback.
// Block: 256 threads (4 waves), one group, 16 positions (4 chains per wave).
__global__ __launch_bounds__(256, 3) void k3_rvq(const float* __restrict__ en32,
                                                 const double* __restrict__ en64,
                                                 const double* __restrict__ zd,
                                                 float* __restrict__ zq,
                                                 double* __restrict__ loss,
                                                 float* __restrict__ out_idx) {
    __shared__ __align__(16) float cb_s[D_ * K_];    // 32 KB, float2 layout [d2][k]
    __shared__ double zd_s[128];                     // 16 pos x 8
    __shared__ double ls[4];
    int tid  = threadIdx.x;
    int wv   = tid >> 6, lane = tid & 63;
    int g     = blockIdx.x / 1200;
    int chunk = blockIdx.x - g * 1200;
    int pos0  = chunk * 16;
    int mypos0 = pos0 + wv * 4;
    size_t zdbase = ((size_t)g * NPOS_ + mypos0) * D_;
    if (tid < 128) zd_s[tid] = zd[((size_t)g * NPOS_ + pos0) * D_ + tid];
    double r[4][8];
    float  rf[4][8];
#pragma unroll
    for (int m = 0; m < 4; m++)
#pragma unroll
        for (int d = 0; d < 8; d++) {
            r[m][d] = zd[zdbase + m * 8 + d];
            rf[m][d] = (float)r[m][d];
        }
    double loss_acc = 0.0;
    const float2* c2 = (const float2*)cb_s;

    for (int i = 0; i < NVQ_; i++) {
        __syncthreads();
        const float4* src = (const float4*)(en32 + ((size_t)(g * NVQ_ + i)) * (D_ * K_));
#pragma unroll
        for (int it = 0; it < 8; it++)
            ((float4*)cb_s)[it * 256 + tid] = src[it * 256 + tid];
        __syncthreads();

        // ---- fp32 screen: per chain track top-1 (val,idx) and top-2 val ----
        float mx1[4], mx2[4]; int ix1[4];
#pragma unroll
        for (int m = 0; m < 4; m++) { mx1[m] = -FLT_MAX; mx2[m] = -FLT_MAX; ix1[m] = 0; }
#pragma unroll
        for (int j = 0; j < 16; j++) {
            int k = j * 64 + lane;
            float2 ca = c2[k];
            float2 cb2 = c2[1024 + k];
            float2 cc = c2[2048 + k];
            float2 cd = c2[3072 + k];
#pragma unroll
            for (int m = 0; m < 4; m++) {
                float s = rf[m][0] * ca.x;
                s = fmaf(rf[m][1], ca.y, s);
                s = fmaf(rf[m][2], cb2.x, s);
                s = fmaf(rf[m][3], cb2.y, s);
                s = fmaf(rf[m][4], cc.x, s);
                s = fmaf(rf[m][5], cc.y, s);
                s = fmaf(rf[m][6], cd.x, s);
                s = fmaf(rf[m][7], cd.y, s);
                float t = fminf(s, mx1[m]);
                mx2[m] = fmaxf(mx2[m], t);
                ix1[m] = (s > mx1[m]) ? k : ix1[m];
                mx1[m] = fmaxf(mx1[m], s);
            }
        }
        // ---- butterfly reduce the (max1, idx1, max2) triples over 64 lanes ----
#pragma unroll
        for (int off = 32; off >= 1; off >>= 1) {
#pragma unroll
            for (int m = 0; m < 4; m++) {
                float o1 = __shfl_xor(mx1[m], off);
                int   oi = __shfl_xor(ix1[m], off);
                float o2 = __shfl_xor(mx2[m], off);
                float lo = fminf(mx1[m], o1);                 // loser of the two top-1s
                mx2[m] = fmaxf(fmaxf(mx2[m], o2), lo);
                if (o1 > mx1[m]) { mx1[m] = o1; ix1[m] = oi; }
            }
        }

        const double* en64g = en64 + ((size_t)(g * NVQ_ + i)) * (K_ * D_);
        // ---- decisions + exact fp64 residual update ----
        for (int m = 0; m < 4; m++) {
            float l1 = fabsf(rf[m][0]);
#pragma unroll
            for (int d = 1; d < 8; d++) l1 += fabsf(rf[m][d]);
            float margin = 2e-6f * l1;     // >= 3x the fp32 dot error bound
            int code;
            if (mx1[m] - mx2[m] > margin) {
                code = ix1[m];             // unique fp64 argmax, proven by margin
            } else {
                // Rare exact path: fp64-rescore all candidates within margin.
                float thr = mx1[m] - margin;
                double best = -DBL_MAX; int bidx = 1 << 20;
                for (int j = 0; j < 16; j++) {
                    int k = j * 64 + lane;
                    float2 ca = c2[k];
                    float2 cb2 = c2[1024 + k];
                    float2 cc = c2[2048 + k];
                    float2 cd = c2[3072 + k];
                    float s = rf[m][0] * ca.x;
                    s = fmaf(rf[m][1], ca.y, s);
                    s = fmaf(rf[m][2], cb2.x, s);
                    s = fmaf(rf[m][3], cb2.y, s);
                    s = fmaf(rf[m][4], cc.x, s);
                    s = fmaf(rf[m][5], cc.y, s);
                    s = fmaf(rf[m][6], cd.x, s);
                    s = fmaf(rf[m][7], cd.y, s);
                    if (s >= thr) {
                        const double* p = en64g + (size_t)k * 8;
                        double s64 = p[0] * r[m][0];
#pragma unroll
                        for (int d = 1; d < 8; d++) s64 = fma(p[d], r[m][d], s64);
                        if (s64 > best) { best = s64; bidx = k; }  // within-lane k ascending: > keeps first
                    }
                }
#pragma unroll
                for (int off = 32; off >= 1; off >>= 1) {
                    double ob = __shfl_xor(best, off);
                    int    oi = __shfl_xor(bidx, off);
                    if (ob > best || (ob == best && oi < bidx)) { best = ob; bidx = oi; }
                }
                code = bidx;
            }
            // exact fp64 residual update from en64 (same-address broadcast, L2-hot)
            const double2* q2 = (const double2*)(en64g + (size_t)code * 8);
            double2 qa = q2[0], qb = q2[1], qc = q2[2], qd = q2[3];
            r[m][0] -= qa.x; r[m][1] -= qa.y;
            r[m][2] -= qb.x; r[m][3] -= qb.y;
            r[m][4] -= qc.x; r[m][5] -= qc.y;
            r[m][6] -= qd.x; r[m][7] -= qd.y;
#pragma unroll
            for (int d = 0; d < 8; d++) {
                loss_acc = fma(r[m][d], r[m][d], loss_acc);
                rf[m][d] = (float)r[m][d];
            }
            if (lane == 0) {
                int pos = mypos0 + m;
                int b = pos / T_, t = pos - b * T_;
                out_idx[((size_t)(b * NVQ_ + i) * G_ + g) * T_ + t] = (float)code;
            }
        }
    }
    // zq = zd - r_final; funnel replicated regs to lanes 0..31 for one coalesced store
    double val = 0.0;
#pragma unroll
    for (int m = 0; m < 4; m++)
#pragma unroll
        for (int d = 0; d < 8; d++) {
            double z = zd_s[wv * 32 + m * 8 + d] - r[m][d];
            if (lane == m * 8 + d) val = z;
        }
    if (lane < 32) zq[zdbase + lane] = (float)val;
    // loss: per-block reduce, one fp64 atomic
    if (lane == 0) ls[wv] = loss_acc;
    __syncthreads();
    if (tid == 0) {
        double s = 0.0;
#pragma unroll
        for (int w2 = 0; w2 < 4; w2++) s += ls[w2];
        atomicAdd(loss, s);
    }
}

// ---------------------------------------------------------------------------
// K4: proj_up + unfold scatter (fp32 is sufficient: 2% threshold). Block: 256
// threads, 4 positions (1/wave). pu staged in LDS with stride-9 rows to break
// the 16-way bank conflict of the natural stride-8 gather. Also writes losses.
__global__ __launch_bounds__(256) void k4_up(const float* __restrict__ zq,
                                             const float* __restrict__ pu,
                                             const double* __restrict__ loss,
                                             float* __restrict__ out_zq,
                                             float* __restrict__ out_loss) {
    __shared__ __align__(16) float pu_s[G_ * GD_ * 9];   // 54 KB, row stride 9
    int tid = threadIdx.x;
#pragma unroll
    for (int it = 0; it < 6; it++) {
        int row = it * 256 + tid;            // 0..1535
        float4 lo = *(const float4*)(pu + (size_t)row * 8);
        float4 hi = *(const float4*)(pu + (size_t)row * 8 + 4);
        float* dst = &pu_s[row * 9];
        dst[0] = lo.x; dst[1] = lo.y; dst[2] = lo.z; dst[3] = lo.w;
        dst[4] = hi.x; dst[5] = hi.y; dst[6] = hi.z; dst[7] = hi.w;
    }
    if (blockIdx.x == 0 && tid == 0) {
        double l = loss[0] * (1.0 / 460800.0);   // /(B*T*D) per group, /G
        out_loss[0] = (float)l;
        out_loss[1] = (float)l;
    }
    __syncthreads();
    int wv = tid >> 6, lane = tid & 63;
    int pos = blockIdx.x * 4 + wv;
    int b = pos / T_, t = pos - b * T_;
    int ov = lane >> 4, c0 = (lane & 15) * 4;
    // A lane's 24 outputs span gd range [gd_min, gd_min+23]: at most 2 groups.
    int gd_min = ov * FIX_ + c0 * 6;
    int g_lo = gd_min >> 9;
    int g_hi = g_lo < 2 ? g_lo + 1 : 2;
    float za[8], zb[8];
    const float* zqa = zq + ((size_t)g_lo * NPOS_ + pos) * D_;
    const float* zqb = zq + ((size_t)g_hi * NPOS_ + pos) * D_;
#pragma unroll
    for (int d = 0; d < 8; d++) { za[d] = zqa[d]; zb[d] = zqb[d]; }
#pragma unroll
    for (int h = 0; h < H_; h++) {
        float4 o;
        float* op = &o.x;
#pragma unroll
        for (int q = 0; q < 4; q++) {
            int gd = ov * FIX_ + (c0 + q) * 6 + h;
            int g  = gd >> 9;
            int j  = gd & 511;
            const float* pr = &pu_s[(g * GD_ + j) * 9];
            bool hi = (g != g_lo);
            float acc = 0.f;
#pragma unroll
            for (int d = 0; d < 8; d++) {
                float zv = hi ? zb[d] : za[d];
                acc = fmaf(zv, pr[d], acc);
            }
            op[q] = acc;
        }
        *(float4*)(out_zq + ((size_t)((b * H_ + h) * W_ + 4 * t + ov)) * C_ + c0) = o;
    }
}

// ---------------------------------------------------------------------------
extern "C" void kernel_launch(void* const* d_in, const int* in_sizes, int n_in,
                              void* d_out, int out_size, void* d_ws, size_t ws_size,
                              hipStream_t stream) {
    const float* ze = (const float*)d_in[0];
    const float* pd = (const float*)d_in[1];
    const float* pu = (const float*)d_in[2];
    const float* cb = (const float*)d_in[3];
    // d_in[4] = num_streams (==6, compile-time NVQ_)

    float* out = (float*)d_out;
    char*  ws  = (char*)d_ws;
    double* ws_en64 = (double*)(ws + WS_EN64);
    float*  ws_en32 = (float*)(ws + WS_EN32);
    double* ws_zd   = (double*)(ws + WS_ZD);
    double* ws_loss = (double*)(ws + WS_LOSS);
    float*  ws_zq   = (float*)(ws + WS_ZQ);

    k1_norm_cb<<<(G_ * NVQ_ * K_ + 255) / 256, 256, 0, stream>>>(cb, ws_en64, ws_en32, ws_loss);
    k2_fold_pd<<<NPOS_ / 8, 256, 0, stream>>>(ze, pd, ws_zd);
    k3_rvq<<<G_ * (NPOS_ / 16), 256, 0, stream>>>(ws_en32, ws_en64, ws_zd, ws_zq, ws_loss, out + OUT_IDX);
    k4_up<<<NPOS_ / 4, 256, 0, stream>>>(ws_zq, pu, ws_loss, out + OUT_ZQ, out + OUT_LOSS);
}